// Round 20
// baseline (252.181 us; speedup 1.0000x reference)
//
#include <hip/hip_runtime.h>
#include <hip/hip_bf16.h>
#include <stdint.h>

#define S_LEN 2048
#define HIDDEN 3584
#define NH 28
#define NKH 4
#define DH 128
#define NG 7          // NH / NKH
#define NQKV 4608     // (NH + 2*NKH) * DH
#define QD 3584       // NH*DH
#define KD 512        // NKH*DH

using bf16x8 = __attribute__((ext_vector_type(8))) __bf16;
using f32x4  = __attribute__((ext_vector_type(4))) float;
using f32x16 = __attribute__((ext_vector_type(16))) float;
using uint2v = __attribute__((ext_vector_type(2))) unsigned;

#define AS3(p) ((__attribute__((address_space(3))) void*)(p))
#define AS1(p) ((const __attribute__((address_space(1))) void*)(p))

__device__ __forceinline__ unsigned short f2bf(float f) {
    unsigned u = __float_as_uint(f);
    u += 0x7FFFu + ((u >> 16) & 1u);
    return (unsigned short)(u >> 16);
}
__device__ __forceinline__ unsigned cvtpk(float a, float b) {
    unsigned r;
    asm("v_cvt_pk_bf16_f32 %0, %1, %2" : "=v"(r) : "v"(a), "v"(b));
    return r;
}
__device__ __forceinline__ float bflo(unsigned u)  { return __uint_as_float(u << 16); }
__device__ __forceinline__ float bfhi(unsigned u)  { return __uint_as_float(u & 0xffff0000u); }
__device__ __forceinline__ float bf1(unsigned short us) { return __uint_as_float((unsigned)us << 16); }

// ---------------- f32 -> bf16 convert (two tensors fused) ----------------
__global__ void cvt2_f32_bf16(const float* __restrict__ a, unsigned short* __restrict__ oa, int na4,
                              const float* __restrict__ b, unsigned short* __restrict__ ob, int nb4) {
    int i = blockIdx.x * blockDim.x + threadIdx.x;
    const float* src;
    unsigned short* dst;
    int n;
    if (i < na4)            { src = a; dst = oa; n = i; }
    else if (i < na4 + nb4) { src = b; dst = ob; n = i - na4; }
    else return;
    float4 v = ((const float4*)src)[n];
    ushort4 o;
    o.x = f2bf(v.x); o.y = f2bf(v.y); o.z = f2bf(v.z); o.w = f2bf(v.w);
    ((ushort4*)dst)[n] = o;
}

// ------------- 256xBN deep-pipelined bf16 GEMM: C = A*B^T (+bias) -------------
template<int BN, bool BF16OUT>
__global__ __launch_bounds__(512, 2) void gemm_deep(
    const unsigned short* __restrict__ A,
    const unsigned short* __restrict__ B,
    void* __restrict__ Cv,
    const float* __restrict__ bias,
    int M, int N, int K)
{
    constexpr int NF    = BN / 32;        // B frags per wave (6 or 4)
    constexpr int HNF   = NF / 2;
    constexpr int WN    = BN / 2;         // cols per wave
    constexpr int VB    = BN / 64;        // B stage loads per thread
    constexpr int TILEB = (256 + BN) * 128;
    __shared__ __align__(16) unsigned char ds[2 * TILEB];

    const int tid  = threadIdx.x;
    const int w    = tid >> 6;
    const int lane = tid & 63;
    const int lr   = lane & 15;
    const int lg   = lane >> 4;
    const int wr   = w >> 1;              // 0..3: M quarter
    const int wc   = w & 1;               // 0..1: N half
    const int m0   = blockIdx.y * 256;
    const int n0   = blockIdx.x * BN;
    const long K2  = (long)K * 2;
    const int scw  = 16 * ((tid & 7) ^ ((tid >> 3) & 7));
    const int srow = tid >> 3;
    const unsigned char* Ab = (const unsigned char*)A;
    const unsigned char* Bb = (const unsigned char*)B;
    const int nk = K >> 6;

    unsigned char* buf0 = ds;
    unsigned char* buf1 = ds + TILEB;

    auto stageB = [&](int kt, unsigned char* bufp) {
        const long kb = (long)kt * 128;
        #pragma unroll
        for (int k = 0; k < VB; ++k)
            __builtin_amdgcn_global_load_lds(
                AS1(Bb + (long)(n0 + k * 64 + srow) * K2 + kb + scw),
                AS3(bufp + k * 8192 + w * 1024), 16, 0, 0);
    };
    auto stageA = [&](int kt, unsigned char* bufp) {
        const long kb = (long)kt * 128;
        #pragma unroll
        for (int k = 0; k < 4; ++k)
            __builtin_amdgcn_global_load_lds(
                AS1(Ab + (long)(m0 + k * 64 + srow) * K2 + kb + scw),
                AS3(bufp + VB * 8192 + k * 8192 + w * 1024), 16, 0, 0);
    };

    f32x4  acc[4][NF] = {};
    bf16x8 af[4][2], bf[NF][2];

    auto readA = [&](const unsigned char* bufp) {
        #pragma unroll
        for (int i = 0; i < 4; ++i) {
            const int row = wr * 64 + i * 16 + lr;
            #pragma unroll
            for (int kk = 0; kk < 2; ++kk)
                af[i][kk] = *(const bf16x8*)(bufp + VB * 8192 + row * 128 +
                                             ((kk * 64 + lg * 16) ^ ((lr & 7) << 4)));
        }
    };
    auto readB = [&](const unsigned char* bufp) {
        #pragma unroll
        for (int ni = 0; ni < NF; ++ni) {
            const int row = wc * WN + ni * 16 + lr;
            #pragma unroll
            for (int kk = 0; kk < 2; ++kk)
                bf[ni][kk] = *(const bf16x8*)(bufp + row * 128 +
                                              ((kk * 64 + lg * 16) ^ ((lr & 7) << 4)));
        }
    };
    auto mfmah = [&](int half) {
        __builtin_amdgcn_s_setprio(1);
        #pragma unroll
        for (int i = 0; i < 4; ++i)
            #pragma unroll
            for (int n2 = 0; n2 < HNF; ++n2) {
                const int ni = half * HNF + n2;
                #pragma unroll
                for (int kk = 0; kk < 2; ++kk)
                    acc[i][ni] = __builtin_amdgcn_mfma_f32_16x16x32_bf16(
                        af[i][kk], bf[ni][kk], acc[i][ni], 0, 0, 0);
            }
        __builtin_amdgcn_s_setprio(0);
    };

    #define VMC() do { if constexpr (VB == 3) asm volatile("s_waitcnt vmcnt(3)" ::: "memory"); \
                       else                   asm volatile("s_waitcnt vmcnt(2)" ::: "memory"); } while (0)
    #define LGK0() do { asm volatile("s_waitcnt lgkmcnt(0)" ::: "memory"); \
                        __builtin_amdgcn_sched_barrier(0); } while (0)

    stageB(0, buf0); stageA(0, buf0); stageB(1, buf1);
    VMC();
    __builtin_amdgcn_s_barrier();

    const int npairs = nk >> 1;
    for (int p = 0; p < npairs; ++p) {
        const int to = 2 * p + 1;
        int te2 = 2 * p + 2; if (te2 >= nk) te2 = nk - 1;
        int to2 = 2 * p + 3; if (to2 >= nk) to2 = nk - 1;

        // ---- tile 2p (buf0) ----
        readA(buf0); readB(buf0);
        stageA(to, buf1);
        __builtin_amdgcn_s_barrier();
        LGK0();
        mfmah(0);
        __builtin_amdgcn_s_barrier();          // all waves done reading buf0.B
        stageB(te2, buf0);
        mfmah(1);
        VMC();                                  // tile 2p+1 fully landed
        __builtin_amdgcn_s_barrier();

        // ---- tile 2p+1 (buf1) ----
        readA(buf1); readB(buf1);
        stageA(te2, buf0);
        __builtin_amdgcn_s_barrier();
        LGK0();
        mfmah(0);
        __builtin_amdgcn_s_barrier();
        stageB(to2, buf1);
        mfmah(1);
        VMC();                                  // tile 2p+2 fully landed
        __builtin_amdgcn_s_barrier();
    }
    asm volatile("s_waitcnt vmcnt(0)" ::: "memory");

    #pragma unroll
    for (int mi = 0; mi < 4; ++mi) {
        #pragma unroll
        for (int ni = 0; ni < NF; ++ni) {
            const int col = n0 + wc * WN + ni * 16 + lr;
            const float bv = bias ? bias[col] : 0.0f;
            #pragma unroll
            for (int j = 0; j < 4; ++j) {
                const int row = m0 + wr * 64 + mi * 16 + lg * 4 + j;
                if constexpr (BF16OUT)
                    ((unsigned short*)Cv)[(long)row * N + col] = f2bf(acc[mi][ni][j] + bv);
                else
                    ((float*)Cv)[(long)row * N + col] = acc[mi][ni][j] + bv;
            }
        }
    }
    #undef VMC
    #undef LGK0
}

// ---------------- QKV post (bf16 in): RMSNorm(q,k) + RoPE, layout shuffle ----------------
__global__ __launch_bounds__(256) void qkv_post(
    const unsigned short* __restrict__ qkv,  // [S][NQKV] bf16 (bias included)
    const int* __restrict__ positions,
    const float* __restrict__ qnw,       // [QD]
    const float* __restrict__ knw,       // [KD]
    unsigned short* __restrict__ qb,     // [NH][S][DH]
    unsigned short* __restrict__ kb,     // [NKH][S][DH]
    unsigned short* __restrict__ vt2)    // [NKH][S/32][DH][32]
{
    const int s   = blockIdx.x;
    const int tid = threadIdx.x;
    const unsigned short* rowp = qkv + (long)s * NQKV;
    __shared__ float red[256];
    __shared__ float s_rq, s_rk;

    float aq = 0.f;
    for (int i = tid; i < QD / 8; i += 256) {
        const unsigned* u2 = (const unsigned*)(rowp + i * 8);
        #pragma unroll
        for (int j = 0; j < 4; ++j) {
            const float lo = bflo(u2[j]), hi = bfhi(u2[j]);
            aq += lo * lo + hi * hi;
        }
    }
    red[tid] = aq; __syncthreads();
    for (int off = 128; off > 0; off >>= 1) {
        if (tid < off) red[tid] += red[tid + off];
        __syncthreads();
    }
    if (tid == 0) s_rq = rsqrtf(red[0] / (float)QD + 1e-6f);
    __syncthreads();

    float ak = 0.f;
    if (tid < KD / 8) {
        const unsigned* u2 = (const unsigned*)(rowp + QD + tid * 8);
        #pragma unroll
        for (int j = 0; j < 4; ++j) {
            const float lo = bflo(u2[j]), hi = bfhi(u2[j]);
            ak += lo * lo + hi * hi;
        }
    }
    red[tid] = ak; __syncthreads();
    for (int off = 128; off > 0; off >>= 1) {
        if (tid < off) red[tid] += red[tid + off];
        __syncthreads();
    }
    if (tid == 0) s_rk = rsqrtf(red[0] / (float)KD + 1e-6f);
    __syncthreads();

    const float rq  = s_rq, rk = s_rk * 0.08838834764831845f;  // fold softmax scale into K
    const float pos = (float)positions[s];
    const float c_lnf = 0.21586735253866598f; // ln(1e6)/64

    for (int u = tid; u < NH * 64; u += 256) {
        const int h = u >> 6, j = u & 63;
        const float inv = expf(-(float)j * c_lnf);
        float sn, cs;
        sincosf(pos * inv, &sn, &cs);
        const float x1 = bf1(rowp[h * DH + j])      * rq * qnw[h * DH + j];
        const float x2 = bf1(rowp[h * DH + 64 + j]) * rq * qnw[h * DH + 64 + j];
        qb[((long)h * S_LEN + s) * DH + j]      = f2bf(x1 * cs - x2 * sn);
        qb[((long)h * S_LEN + s) * DH + 64 + j] = f2bf(x2 * cs + x1 * sn);
    }
    for (int u = tid; u < NKH * 64; u += 256) {
        const int h = u >> 6, j = u & 63;
        const float inv = expf(-(float)j * c_lnf);
        float sn, cs;
        sincosf(pos * inv, &sn, &cs);
        const float x1 = bf1(rowp[QD + h * DH + j])      * rk * knw[h * DH + j];
        const float x2 = bf1(rowp[QD + h * DH + 64 + j]) * rk * knw[h * DH + 64 + j];
        kb[((long)h * S_LEN + s) * DH + j]      = f2bf(x1 * cs - x2 * sn);
        kb[((long)h * S_LEN + s) * DH + 64 + j] = f2bf(x2 * cs + x1 * sn);
    }
    // V -> tiled-transposed: vt2[kh][s/32][d][s%32] (raw bf16 copy)
    for (int u = tid; u < KD; u += 256) {
        const int hh = u >> 7, d = u & 127;
        vt2[(((long)hh * (S_LEN / 32) + (s >> 5)) * DH + d) * 32 + (s & 31)] =
            rowp[QD + KD + u];
    }
}

// ------- flash attention kv-split (permlane pack) + o_w-convert backfill -------
// z takes kv tiles {z, z+2, ...} (disjoint -> no duplicate staging); 512 attn blocks
// = 2/CU. bf16 partials (O) + f32 (m,l) merged by attn_combine. bx>=64 & z==0:
// backfill blocks grid-stride convert o_w f32 -> bf16.
__global__ __launch_bounds__(512) void attn_split(
    const unsigned short* __restrict__ qb,   // [NH][S][DH]
    const unsigned short* __restrict__ kb,   // [NKH][S][DH] (pre-scaled)
    const unsigned short* __restrict__ vt2,  // [NKH][S/32][DH][32]
    unsigned short* __restrict__ pOb,        // [2][NKH][64][7] x 32x128 bf16
    float* __restrict__ pml,                 // [2][NKH][64][7] x {m[32], l[32]}
    const float* __restrict__ ow,            // [HIDDEN*QD] f32
    unsigned short* __restrict__ w2)         // [HIDDEN*QD] bf16
{
    const int tid = threadIdx.x;

    if (blockIdx.x >= 64) {
        if (blockIdx.z != 0) return;
        const int ci = (blockIdx.x - 64) * NKH + blockIdx.y;   // 0..127
        const int n4 = HIDDEN * QD / 4;
        for (int i = ci * 512 + tid; i < n4; i += 128 * 512) {
            float4 v = ((const float4*)ow)[i];
            ushort4 o;
            o.x = f2bf(v.x); o.y = f2bf(v.y); o.z = f2bf(v.z); o.w = f2bf(v.w);
            ((ushort4*)w2)[i] = o;
        }
        return;
    }

    __shared__ __align__(16) unsigned char sK[2][8192];  // [32 s][16 ch 16B], ch ^ (row&15)
    __shared__ __align__(16) unsigned char sV[2][8192];  // [128 d][4 ch 16B], ch ^ ((row>>1)&3)

    const int qt   = 63 - blockIdx.x;        // big q-tiles dispatched first
    const int kh   = blockIdx.y;
    const int z    = blockIdx.z;
    const int w    = tid >> 6;
    const int lane = tid & 63;
    const int lq   = lane & 31;
    const int hi   = lane >> 5;
    const int hi8  = hi * 8;
    const int hi4  = hi * 4;
    const int q0   = qt * 32;
    const int NT   = qt + 1;

    const unsigned char* kgb = (const unsigned char*)(kb + (long)kh * S_LEN * DH);
    const unsigned char* vgb = (const unsigned char*)vt2 + (long)kh * (S_LEN / 32) * 8192;

    const int ksrc_off = (((tid & 15) ^ (tid >> 4)) & 15) << 4;
    const int u        = tid & 255;
    const int vsrc_off = ((u & 3) ^ ((u >> 3) & 3)) << 4;

    const float RTHR = 8.0f;   // defer-max threshold (scale already folded into K)

    auto stage = [&](int t, int b) {
        if (tid < 256) {
            const unsigned char* ks = kgb + (long)t * 8192;
            #pragma unroll
            for (int j = 0; j < 2; ++j)
                __builtin_amdgcn_global_load_lds(AS1(ks + ((tid >> 4) + 16 * j) * 256 + ksrc_off),
                                                 AS3(&sK[b][0] + w * 1024 + j * 4096), 16, 0, 0);
        } else {
            const unsigned char* vs = vgb + (long)t * 8192;
            #pragma unroll
            for (int j = 0; j < 2; ++j)
                __builtin_amdgcn_global_load_lds(AS1(vs + ((u >> 2) + 64 * j) * 64 + vsrc_off),
                                                 AS3(&sV[b][0] + (w - 4) * 1024 + j * 4096), 16, 0, 0);
        }
    };

    bf16x8 qf[8];
    if (w < 7) {
        const int h = kh * NG + w;
        const unsigned short* qrow = qb + ((long)h * S_LEN + q0 + lq) * DH;
        #pragma unroll
        for (int c = 0; c < 8; ++c)
            qf[c] = *(const bf16x8*)(qrow + c * 16 + hi8);
    }

    f32x16 o[4] = {};
    float m = -3e38f;
    float l = 0.f;

    stage(z, 0);

    int ii = 0;
    for (int t = z; t < NT; t += 2, ++ii) {
        __syncthreads();   // drains vmcnt: buf[ii&1] ready

        if (t + 2 < NT) stage(t + 2, (ii + 1) & 1);

        if (w < 7) {
            const unsigned char* sKb = sK[ii & 1];
            const unsigned char* sVb = sV[ii & 1];

            bf16x8 kf[8];
            #pragma unroll
            for (int c = 0; c < 8; ++c)
                kf[c] = *(const bf16x8*)(sKb + lq * 256 + (((2 * c + hi) ^ (lq & 15)) << 4));
            f32x16 sc = {};
            __builtin_amdgcn_s_setprio(1);
            #pragma unroll
            for (int c = 0; c < 8; ++c)
                sc = __builtin_amdgcn_mfma_f32_32x32x16_bf16(kf[c], qf[c], sc, 0, 0, 0);
            __builtin_amdgcn_s_setprio(0);

            float s[16];
            if (t == NT - 1) {
                #pragma unroll
                for (int r = 0; r < 16; ++r) {
                    const int kr = (r & 3) + 8 * (r >> 2) + hi4;
                    s[r] = (kr > lq) ? -3e38f : sc[r];
                }
            } else {
                #pragma unroll
                for (int r = 0; r < 16; ++r) s[r] = sc[r];
            }

            float mx = s[0];
            #pragma unroll
            for (int r = 1; r < 16; ++r) mx = fmaxf(mx, s[r]);
            mx = fmaxf(mx, __shfl_xor(mx, 32));

            if (!__all(mx <= m + RTHR)) {
                const float nm  = fmaxf(m, mx);
                const float fac = __expf(m - nm);
                l *= fac;
                #pragma unroll
                for (int d0 = 0; d0 < 4; ++d0)
                    #pragma unroll
                    for (int r = 0; r < 16; ++r) o[d0][r] *= fac;
                m = nm;
            }

            float p[16];
            float ps = 0.f;
            #pragma unroll
            for (int r = 0; r < 16; ++r) {
                p[r] = __expf(s[r] - m);
                ps += p[r];
            }
            ps += __shfl_xor(ps, 32);
            l += ps;

            // ---- P -> PV B-fragments: cvt_pk + permlane32_swap (VALU, no LDS pipe) ----
            unsigned pa01 = cvtpk(p[0],  p[1]),  pa23 = cvtpk(p[2],  p[3]);
            unsigned pb01 = cvtpk(p[4],  p[5]),  pb23 = cvtpk(p[6],  p[7]);
            unsigned pc01 = cvtpk(p[8],  p[9]),  pc23 = cvtpk(p[10], p[11]);
            unsigned pd01 = cvtpk(p[12], p[13]), pd23 = cvtpk(p[14], p[15]);
            uint2v r0 = __builtin_amdgcn_permlane32_swap(pa01, pb01, false, false);
            uint2v r1 = __builtin_amdgcn_permlane32_swap(pa23, pb23, false, false);
            uint2v r2 = __builtin_amdgcn_permlane32_swap(pc01, pd01, false, false);
            uint2v r3 = __builtin_amdgcn_permlane32_swap(pc23, pd23, false, false);

            union { unsigned uu[4]; bf16x8 v; } pf0, pf1;
            pf0.uu[0] = r0[0];
            pf0.uu[1] = r1[0];
            pf0.uu[2] = r0[1];
            pf0.uu[3] = r1[1];
            pf1.uu[0] = r2[0];
            pf1.uu[1] = r3[0];
            pf1.uu[2] = r2[1];
            pf1.uu[3] = r3[1];

            #pragma unroll
            for (int d0 = 0; d0 < 4; ++d0) {
                const int row = d0 * 32 + lq;
                const int sw  = (lq >> 1) & 3;
                bf16x8 vf0 = *(const bf16x8*)(sVb + row * 64 + ((hi ^ sw) << 4));
                bf16x8 vf1 = *(const bf16x8*)(sVb + row * 64 + (((2 + hi) ^ sw) << 4));
                __builtin_amdgcn_s_setprio(1);
                o[d0] = __builtin_amdgcn_mfma_f32_32x32x16_bf16(vf0, pf0.v, o[d0], 0, 0, 0);
                o[d0] = __builtin_amdgcn_mfma_f32_32x32x16_bf16(vf1, pf1.v, o[d0], 0, 0, 0);
                __builtin_amdgcn_s_setprio(0);
            }
        }
    }

    if (w == 7) return;

    // ---- write bf16 O partials + f32 m,l ----
    const long rec = ((long)(z * NKH + kh) * 64 + qt) * 7 + w;
    unsigned short* Orec = pOb + rec * 4096;    // [32 q][128 d] bf16
    #pragma unroll
    for (int d0 = 0; d0 < 4; ++d0) {
        #pragma unroll
        for (int g = 0; g < 4; ++g) {
            uint2v pk;
            pk[0] = cvtpk(o[d0][4 * g + 0], o[d0][4 * g + 1]);
            pk[1] = cvtpk(o[d0][4 * g + 2], o[d0][4 * g + 3]);
            *(uint2v*)(Orec + lq * 128 + d0 * 32 + 8 * g + hi4) = pk;
        }
    }
    if (hi == 0) {
        pml[rec * 64 + lq]      = m;
        pml[rec * 64 + 32 + lq] = l;
    }
}

// ---------------- combine the two kv-half partials -> bf16 attn output ----------------
__global__ __launch_bounds__(256) void attn_combine(
    const unsigned short* __restrict__ pOb,
    const float* __restrict__ pml,
    unsigned short* __restrict__ attnb)      // [S][QD]
{
    const int qt  = blockIdx.x;
    const int h   = blockIdx.y;
    const int kh  = h / NG;
    const int wh  = h % NG;
    const int tid = threadIdx.x;
    const int q   = tid >> 3;
    const int dg  = (tid & 7) * 16;

    const long rec0 = ((long)kh * 64 + qt) * 7 + wh;
    const long rec1 = rec0 + (long)NKH * 64 * 7;
    const float m0 = pml[rec0 * 64 + q], l0 = pml[rec0 * 64 + 32 + q];
    const float m1 = pml[rec1 * 64 + q], l1 = pml[rec1 * 64 + 32 + q];
    const float M  = fmaxf(m0, m1);
    const float f0 = __expf(m0 - M);
    const float f1 = __expf(m1 - M);
    const float rl = 1.0f / (l0 * f0 + l1 * f1);

    const unsigned short* O0 = pOb + rec0 * 4096 + q * 128 + dg;
    const unsigned short* O1 = pOb + rec1 * 4096 + q * 128 + dg;
    unsigned short* orow = attnb + (long)(qt * 32 + q) * QD + h * DH + dg;
    #pragma unroll
    for (int i = 0; i < 2; ++i) {
        uint4 a = *(const uint4*)(O0 + i * 8);
        uint4 b = *(const uint4*)(O1 + i * 8);
        ushort4 s0, s1;
        s0.x = f2bf((f0 * bflo(a.x) + f1 * bflo(b.x)) * rl);
        s0.y = f2bf((f0 * bfhi(a.x) + f1 * bfhi(b.x)) * rl);
        s0.z = f2bf((f0 * bflo(a.y) + f1 * bflo(b.y)) * rl);
        s0.w = f2bf((f0 * bfhi(a.y) + f1 * bfhi(b.y)) * rl);
        s1.x = f2bf((f0 * bflo(a.z) + f1 * bflo(b.z)) * rl);
        s1.y = f2bf((f0 * bfhi(a.z) + f1 * bfhi(b.z)) * rl);
        s1.z = f2bf((f0 * bflo(a.w) + f1 * bflo(b.w)) * rl);
        s1.w = f2bf((f0 * bfhi(a.w) + f1 * bfhi(b.w)) * rl);
        *(ushort4*)(orow + i * 8)     = s0;
        *(ushort4*)(orow + i * 8 + 4) = s1;
    }
}

// ---------------- launch ----------------
extern "C" void kernel_launch(void* const* d_in, const int* in_sizes, int n_in,
                              void* d_out, int out_size, void* d_ws, size_t ws_size,
                              hipStream_t stream) {
    const int*   positions = (const int*)d_in[0];
    const float* hidden    = (const float*)d_in[1];
    const float* qkv_w     = (const float*)d_in[2];
    const float* qkv_b     = (const float*)d_in[3];
    const float* qnw       = (const float*)d_in[4];
    const float* knw       = (const float*)d_in[5];
    const float* o_w       = (const float*)d_in[6];
    float* out = (float*)d_out;

    unsigned char* ws = (unsigned char*)d_ws;
    unsigned short* hb    = (unsigned short*)(ws);               // 14,680,064 B
    unsigned short* w1    = (unsigned short*)(ws + 14680064);    // 33,030,144 B
    unsigned short* qkvb  = (unsigned short*)(ws + 47710208);    // 18,874,368 B (bf16 qkv)
    unsigned short* qbuf  = (unsigned short*)(ws + 85458944);    // 14,680,064 B
    unsigned short* kbuf  = (unsigned short*)(ws + 100139008);   //  2,097,152 B
    unsigned short* vtb   = (unsigned short*)(ws + 102236160);   //  2,097,152 B
    unsigned short* attnb = (unsigned short*)(ws);               // reuse hb (dead after GEMM1)
    unsigned short* w2    = (unsigned short*)(ws + 14680064);    // reuse w1 (dead after GEMM1)
    unsigned short* pOb   = (unsigned short*)(ws + 47710208);    // 29,360,128 B (reuse qkvb)
    float*          pml   = (float*)(ws + 77070336);             //    917,504 B (free gap)

    const int na4 = S_LEN * HIDDEN / 4;
    const int nb4 = NQKV * HIDDEN / 4;
    cvt2_f32_bf16<<<(na4 + nb4 + 255) / 256, 256, 0, stream>>>(hidden, hb, na4, qkv_w, w1, nb4);
    gemm_deep<192, true><<<dim3(NQKV / 192, S_LEN / 256), 512, 0, stream>>>(
        hb, w1, qkvb, qkv_b, S_LEN, NQKV, HIDDEN);
    qkv_post<<<S_LEN, 256, 0, stream>>>(qkvb, positions, qnw, knw, qbuf, kbuf, vtb);
    attn_split<<<dim3(64 + 32, NKH, 2), 512, 0, stream>>>(qbuf, kbuf, vtb, pOb, pml, o_w, w2);
    attn_combine<<<dim3(S_LEN / 32, NH), 256, 0, stream>>>(pOb, pml, attnb);
    gemm_deep<128, false><<<dim3(HIDDEN / 128, S_LEN / 256), 512, 0, stream>>>(
        attnb, w2, out, nullptr, S_LEN, HIDDEN, QD);
}

// Round 21
// 239.622 us; speedup vs baseline: 1.0524x; 1.0524x over previous
//
#include <hip/hip_runtime.h>
#include <hip/hip_bf16.h>
#include <stdint.h>

#define S_LEN 2048
#define HIDDEN 3584
#define NH 28
#define NKH 4
#define DH 128
#define NG 7          // NH / NKH
#define NQKV 4608     // (NH + 2*NKH) * DH
#define QD 3584       // NH*DH
#define KD 512        // NKH*DH

using bf16x8 = __attribute__((ext_vector_type(8))) __bf16;
using f32x4  = __attribute__((ext_vector_type(4))) float;
using f32x16 = __attribute__((ext_vector_type(16))) float;
using uint2v = __attribute__((ext_vector_type(2))) unsigned;

#define AS3(p) ((__attribute__((address_space(3))) void*)(p))
#define AS1(p) ((const __attribute__((address_space(1))) void*)(p))

__device__ __forceinline__ unsigned short f2bf(float f) {
    unsigned u = __float_as_uint(f);
    u += 0x7FFFu + ((u >> 16) & 1u);
    return (unsigned short)(u >> 16);
}
__device__ __forceinline__ unsigned cvtpk(float a, float b) {
    unsigned r;
    asm("v_cvt_pk_bf16_f32 %0, %1, %2" : "=v"(r) : "v"(a), "v"(b));
    return r;
}
__device__ __forceinline__ float bflo(unsigned u)  { return __uint_as_float(u << 16); }
__device__ __forceinline__ float bfhi(unsigned u)  { return __uint_as_float(u & 0xffff0000u); }
__device__ __forceinline__ float bf1(unsigned short us) { return __uint_as_float((unsigned)us << 16); }

// ---------------- f32 -> bf16 convert (two tensors fused) ----------------
__global__ void cvt2_f32_bf16(const float* __restrict__ a, unsigned short* __restrict__ oa, int na4,
                              const float* __restrict__ b, unsigned short* __restrict__ ob, int nb4) {
    int i = blockIdx.x * blockDim.x + threadIdx.x;
    const float* src;
    unsigned short* dst;
    int n;
    if (i < na4)            { src = a; dst = oa; n = i; }
    else if (i < na4 + nb4) { src = b; dst = ob; n = i - na4; }
    else return;
    float4 v = ((const float4*)src)[n];
    ushort4 o;
    o.x = f2bf(v.x); o.y = f2bf(v.y); o.z = f2bf(v.z); o.w = f2bf(v.w);
    ((ushort4*)dst)[n] = o;
}

// ------------- 256xBN deep-pipelined bf16 GEMM: C = A*B^T (+bias) -------------
// BF16OUT: epilogue rounds to bf16 (bias added in f32 first) -> halves C traffic.
template<int BN, bool BF16OUT>
__global__ __launch_bounds__(512, 2) void gemm_deep(
    const unsigned short* __restrict__ A,
    const unsigned short* __restrict__ B,
    void* __restrict__ Cv,
    const float* __restrict__ bias,
    int M, int N, int K)
{
    constexpr int NF    = BN / 32;        // B frags per wave (6 or 4)
    constexpr int HNF   = NF / 2;
    constexpr int WN    = BN / 2;         // cols per wave
    constexpr int VB    = BN / 64;        // B stage loads per thread
    constexpr int TILEB = (256 + BN) * 128;
    __shared__ __align__(16) unsigned char ds[2 * TILEB];

    const int tid  = threadIdx.x;
    const int w    = tid >> 6;
    const int lane = tid & 63;
    const int lr   = lane & 15;
    const int lg   = lane >> 4;
    const int wr   = w >> 1;              // 0..3: M quarter
    const int wc   = w & 1;               // 0..1: N half
    const int m0   = blockIdx.y * 256;
    const int n0   = blockIdx.x * BN;
    const long K2  = (long)K * 2;
    const int scw  = 16 * ((tid & 7) ^ ((tid >> 3) & 7));
    const int srow = tid >> 3;
    const unsigned char* Ab = (const unsigned char*)A;
    const unsigned char* Bb = (const unsigned char*)B;
    const int nk = K >> 6;

    unsigned char* buf0 = ds;
    unsigned char* buf1 = ds + TILEB;

    auto stageB = [&](int kt, unsigned char* bufp) {
        const long kb = (long)kt * 128;
        #pragma unroll
        for (int k = 0; k < VB; ++k)
            __builtin_amdgcn_global_load_lds(
                AS1(Bb + (long)(n0 + k * 64 + srow) * K2 + kb + scw),
                AS3(bufp + k * 8192 + w * 1024), 16, 0, 0);
    };
    auto stageA = [&](int kt, unsigned char* bufp) {
        const long kb = (long)kt * 128;
        #pragma unroll
        for (int k = 0; k < 4; ++k)
            __builtin_amdgcn_global_load_lds(
                AS1(Ab + (long)(m0 + k * 64 + srow) * K2 + kb + scw),
                AS3(bufp + VB * 8192 + k * 8192 + w * 1024), 16, 0, 0);
    };

    f32x4  acc[4][NF] = {};
    bf16x8 af[4][2], bf[NF][2];

    auto readA = [&](const unsigned char* bufp) {
        #pragma unroll
        for (int i = 0; i < 4; ++i) {
            const int row = wr * 64 + i * 16 + lr;
            #pragma unroll
            for (int kk = 0; kk < 2; ++kk)
                af[i][kk] = *(const bf16x8*)(bufp + VB * 8192 + row * 128 +
                                             ((kk * 64 + lg * 16) ^ ((lr & 7) << 4)));
        }
    };
    auto readB = [&](const unsigned char* bufp) {
        #pragma unroll
        for (int ni = 0; ni < NF; ++ni) {
            const int row = wc * WN + ni * 16 + lr;
            #pragma unroll
            for (int kk = 0; kk < 2; ++kk)
                bf[ni][kk] = *(const bf16x8*)(bufp + row * 128 +
                                              ((kk * 64 + lg * 16) ^ ((lr & 7) << 4)));
        }
    };
    auto mfmah = [&](int half) {
        __builtin_amdgcn_s_setprio(1);
        #pragma unroll
        for (int i = 0; i < 4; ++i)
            #pragma unroll
            for (int n2 = 0; n2 < HNF; ++n2) {
                const int ni = half * HNF + n2;
                #pragma unroll
                for (int kk = 0; kk < 2; ++kk)
                    acc[i][ni] = __builtin_amdgcn_mfma_f32_16x16x32_bf16(
                        af[i][kk], bf[ni][kk], acc[i][ni], 0, 0, 0);
            }
        __builtin_amdgcn_s_setprio(0);
    };

    #define VMC() do { if constexpr (VB == 3) asm volatile("s_waitcnt vmcnt(3)" ::: "memory"); \
                       else                   asm volatile("s_waitcnt vmcnt(2)" ::: "memory"); } while (0)
    #define LGK0() do { asm volatile("s_waitcnt lgkmcnt(0)" ::: "memory"); \
                        __builtin_amdgcn_sched_barrier(0); } while (0)

    stageB(0, buf0); stageA(0, buf0); stageB(1, buf1);
    VMC();
    __builtin_amdgcn_s_barrier();

    const int npairs = nk >> 1;
    for (int p = 0; p < npairs; ++p) {
        const int to = 2 * p + 1;
        int te2 = 2 * p + 2; if (te2 >= nk) te2 = nk - 1;
        int to2 = 2 * p + 3; if (to2 >= nk) to2 = nk - 1;

        // ---- tile 2p (buf0) ----
        readA(buf0); readB(buf0);
        stageA(to, buf1);
        __builtin_amdgcn_s_barrier();
        LGK0();
        mfmah(0);
        __builtin_amdgcn_s_barrier();          // all waves done reading buf0.B
        stageB(te2, buf0);
        mfmah(1);
        VMC();                                  // tile 2p+1 fully landed
        __builtin_amdgcn_s_barrier();

        // ---- tile 2p+1 (buf1) ----
        readA(buf1); readB(buf1);
        stageA(te2, buf0);
        __builtin_amdgcn_s_barrier();
        LGK0();
        mfmah(0);
        __builtin_amdgcn_s_barrier();
        stageB(to2, buf1);
        mfmah(1);
        VMC();                                  // tile 2p+2 fully landed
        __builtin_amdgcn_s_barrier();
    }
    asm volatile("s_waitcnt vmcnt(0)" ::: "memory");

    #pragma unroll
    for (int mi = 0; mi < 4; ++mi) {
        #pragma unroll
        for (int ni = 0; ni < NF; ++ni) {
            const int col = n0 + wc * WN + ni * 16 + lr;
            const float bv = bias ? bias[col] : 0.0f;
            #pragma unroll
            for (int j = 0; j < 4; ++j) {
                const int row = m0 + wr * 64 + mi * 16 + lg * 4 + j;
                if constexpr (BF16OUT)
                    ((unsigned short*)Cv)[(long)row * N + col] = f2bf(acc[mi][ni][j] + bv);
                else
                    ((float*)Cv)[(long)row * N + col] = acc[mi][ni][j] + bv;
            }
        }
    }
    #undef VMC
    #undef LGK0
}

// ---------------- QKV post (bf16 in): RMSNorm(q,k) + RoPE, layout shuffle ----------------
__global__ __launch_bounds__(256) void qkv_post(
    const unsigned short* __restrict__ qkv,  // [S][NQKV] bf16 (bias included)
    const int* __restrict__ positions,
    const float* __restrict__ qnw,       // [QD]
    const float* __restrict__ knw,       // [KD]
    unsigned short* __restrict__ qb,     // [NH][S][DH]
    unsigned short* __restrict__ kb,     // [NKH][S][DH]
    unsigned short* __restrict__ vt2)    // [NKH][S/32][DH][32]
{
    const int s   = blockIdx.x;
    const int tid = threadIdx.x;
    const unsigned short* rowp = qkv + (long)s * NQKV;
    __shared__ float red[256];
    __shared__ float s_rq, s_rk;

    float aq = 0.f;
    for (int i = tid; i < QD / 8; i += 256) {
        const unsigned* u2 = (const unsigned*)(rowp + i * 8);
        #pragma unroll
        for (int j = 0; j < 4; ++j) {
            const float lo = bflo(u2[j]), hi = bfhi(u2[j]);
            aq += lo * lo + hi * hi;
        }
    }
    red[tid] = aq; __syncthreads();
    for (int off = 128; off > 0; off >>= 1) {
        if (tid < off) red[tid] += red[tid + off];
        __syncthreads();
    }
    if (tid == 0) s_rq = rsqrtf(red[0] / (float)QD + 1e-6f);
    __syncthreads();

    float ak = 0.f;
    if (tid < KD / 8) {
        const unsigned* u2 = (const unsigned*)(rowp + QD + tid * 8);
        #pragma unroll
        for (int j = 0; j < 4; ++j) {
            const float lo = bflo(u2[j]), hi = bfhi(u2[j]);
            ak += lo * lo + hi * hi;
        }
    }
    red[tid] = ak; __syncthreads();
    for (int off = 128; off > 0; off >>= 1) {
        if (tid < off) red[tid] += red[tid + off];
        __syncthreads();
    }
    if (tid == 0) s_rk = rsqrtf(red[0] / (float)KD + 1e-6f);
    __syncthreads();

    const float rq  = s_rq, rk = s_rk * 0.08838834764831845f;  // fold softmax scale into K
    const float pos = (float)positions[s];
    const float c_lnf = 0.21586735253866598f; // ln(1e6)/64

    for (int u = tid; u < NH * 64; u += 256) {
        const int h = u >> 6, j = u & 63;
        const float inv = expf(-(float)j * c_lnf);
        float sn, cs;
        sincosf(pos * inv, &sn, &cs);
        const float x1 = bf1(rowp[h * DH + j])      * rq * qnw[h * DH + j];
        const float x2 = bf1(rowp[h * DH + 64 + j]) * rq * qnw[h * DH + 64 + j];
        qb[((long)h * S_LEN + s) * DH + j]      = f2bf(x1 * cs - x2 * sn);
        qb[((long)h * S_LEN + s) * DH + 64 + j] = f2bf(x2 * cs + x1 * sn);
    }
    for (int u = tid; u < NKH * 64; u += 256) {
        const int h = u >> 6, j = u & 63;
        const float inv = expf(-(float)j * c_lnf);
        float sn, cs;
        sincosf(pos * inv, &sn, &cs);
        const float x1 = bf1(rowp[QD + h * DH + j])      * rk * knw[h * DH + j];
        const float x2 = bf1(rowp[QD + h * DH + 64 + j]) * rk * knw[h * DH + 64 + j];
        kb[((long)h * S_LEN + s) * DH + j]      = f2bf(x1 * cs - x2 * sn);
        kb[((long)h * S_LEN + s) * DH + 64 + j] = f2bf(x2 * cs + x1 * sn);
    }
    // V -> tiled-transposed: vt2[kh][s/32][d][s%32] (raw bf16 copy)
    for (int u = tid; u < KD; u += 256) {
        const int hh = u >> 7, d = u & 127;
        vt2[(((long)hh * (S_LEN / 32) + (s >> 5)) * DH + d) * 32 + (s & 31)] =
            rowp[QD + KD + u];
    }
}

// ---------------- flash attention + o_w-convert backfill ----------------
// bx < 64: attention (verified path). bx >= 64: 64 backfill blocks grid-stride
// convert o_w f32 -> bf16 (fills CUs freed by short causal blocks; disjoint writes).
__global__ __launch_bounds__(512) void attn_fwd(
    const unsigned short* __restrict__ qb,   // [NH][S][DH]
    const unsigned short* __restrict__ kb,   // [NKH][S][DH] (pre-scaled)
    const unsigned short* __restrict__ vt2,  // [NKH][S/32][DH][32]
    unsigned short* __restrict__ attnb,      // [S][QD]
    const float* __restrict__ ow,            // [HIDDEN*QD] f32
    unsigned short* __restrict__ w2)         // [HIDDEN*QD] bf16
{
    const int tid  = threadIdx.x;

    if (blockIdx.x >= 64) {
        // ---- backfill: convert o_w ----
        const int ci = (blockIdx.x - 64) * NKH + blockIdx.y;   // 0..63
        const int n4 = HIDDEN * QD / 4;
        for (int i = ci * 512 + tid; i < n4; i += 64 * 512) {
            float4 v = ((const float4*)ow)[i];
            ushort4 o;
            o.x = f2bf(v.x); o.y = f2bf(v.y); o.z = f2bf(v.z); o.w = f2bf(v.w);
            ((ushort4*)w2)[i] = o;
        }
        return;
    }

    __shared__ __align__(16) unsigned char sK[2][8192];  // [32 s][16 ch 16B], ch ^ (row&15)
    __shared__ __align__(16) unsigned char sV[2][8192];  // [128 d][4 ch 16B], ch ^ ((row>>1)&3)

    const int qt   = 63 - blockIdx.x;        // big q-tiles dispatched first
    const int kh   = blockIdx.y;
    const int w    = tid >> 6;
    const int lane = tid & 63;
    const int lq   = lane & 31;
    const int hi   = lane >> 5;
    const int hi8  = hi * 8;
    const int hi4  = hi * 4;
    const int q0   = qt * 32;
    const int NT   = qt + 1;

    const unsigned char* kgb = (const unsigned char*)(kb + (long)kh * S_LEN * DH);
    const unsigned char* vgb = (const unsigned char*)vt2 + (long)kh * (S_LEN / 32) * 8192;

    const int ksrc_off = (((tid & 15) ^ (tid >> 4)) & 15) << 4;
    const int u        = tid & 255;
    const int vsrc_off = ((u & 3) ^ ((u >> 3) & 3)) << 4;

    const float RTHR = 8.0f;   // defer-max threshold (scale already folded into K)

    bf16x8 qf[8];
    if (w < 7) {
        const int h = kh * NG + w;
        const unsigned short* qrow = qb + ((long)h * S_LEN + q0 + lq) * DH;
        #pragma unroll
        for (int c = 0; c < 8; ++c)
            qf[c] = *(const bf16x8*)(qrow + c * 16 + hi8);
    }

    f32x16 o[4] = {};
    float m = -3e38f;
    float l = 0.f;

    if (tid < 256) {
        #pragma unroll
        for (int j = 0; j < 2; ++j)
            __builtin_amdgcn_global_load_lds(AS1(kgb + ((tid >> 4) + 16 * j) * 256 + ksrc_off),
                                             AS3(&sK[0][0] + w * 1024 + j * 4096), 16, 0, 0);
    } else {
        #pragma unroll
        for (int j = 0; j < 2; ++j)
            __builtin_amdgcn_global_load_lds(AS1(vgb + ((u >> 2) + 64 * j) * 64 + vsrc_off),
                                             AS3(&sV[0][0] + (w - 4) * 1024 + j * 4096), 16, 0, 0);
    }

    for (int t = 0; t < NT; ++t) {
        __syncthreads();   // drains vmcnt: buf[t&1] ready

        if (t + 1 < NT) {
            const int b = (t + 1) & 1;
            if (tid < 256) {
                const unsigned char* ks = kgb + (long)(t + 1) * 8192;
                #pragma unroll
                for (int j = 0; j < 2; ++j)
                    __builtin_amdgcn_global_load_lds(AS1(ks + ((tid >> 4) + 16 * j) * 256 + ksrc_off),
                                                     AS3(&sK[b][0] + w * 1024 + j * 4096), 16, 0, 0);
            } else {
                const unsigned char* vs = vgb + (long)(t + 1) * 8192;
                #pragma unroll
                for (int j = 0; j < 2; ++j)
                    __builtin_amdgcn_global_load_lds(AS1(vs + ((u >> 2) + 64 * j) * 64 + vsrc_off),
                                                     AS3(&sV[b][0] + (w - 4) * 1024 + j * 4096), 16, 0, 0);
            }
        }

        if (w < 7) {
            const unsigned char* sKb = sK[t & 1];
            const unsigned char* sVb = sV[t & 1];

            bf16x8 kf[8];
            #pragma unroll
            for (int c = 0; c < 8; ++c)
                kf[c] = *(const bf16x8*)(sKb + lq * 256 + (((2 * c + hi) ^ (lq & 15)) << 4));
            f32x16 sc = {};
            __builtin_amdgcn_s_setprio(1);
            #pragma unroll
            for (int c = 0; c < 8; ++c)
                sc = __builtin_amdgcn_mfma_f32_32x32x16_bf16(kf[c], qf[c], sc, 0, 0, 0);
            __builtin_amdgcn_s_setprio(0);

            float s[16];
            if (t == NT - 1) {
                #pragma unroll
                for (int r = 0; r < 16; ++r) {
                    const int kr = (r & 3) + 8 * (r >> 2) + hi4;
                    s[r] = (kr > lq) ? -3e38f : sc[r];
                }
            } else {
                #pragma unroll
                for (int r = 0; r < 16; ++r) s[r] = sc[r];
            }

            float mx = s[0];
            #pragma unroll
            for (int r = 1; r < 16; ++r) mx = fmaxf(mx, s[r]);
            mx = fmaxf(mx, __shfl_xor(mx, 32));

            if (!__all(mx <= m + RTHR)) {
                const float nm  = fmaxf(m, mx);
                const float fac = __expf(m - nm);
                l *= fac;
                #pragma unroll
                for (int d0 = 0; d0 < 4; ++d0)
                    #pragma unroll
                    for (int r = 0; r < 16; ++r) o[d0][r] *= fac;
                m = nm;
            }

            float p[16];
            float ps = 0.f;
            #pragma unroll
            for (int r = 0; r < 16; ++r) {
                p[r] = __expf(s[r] - m);
                ps += p[r];
            }
            ps += __shfl_xor(ps, 32);
            l += ps;

            // ---- P -> PV B-fragments: cvt_pk + permlane32_swap (VALU, no LDS pipe) ----
            unsigned pa01 = cvtpk(p[0],  p[1]),  pa23 = cvtpk(p[2],  p[3]);
            unsigned pb01 = cvtpk(p[4],  p[5]),  pb23 = cvtpk(p[6],  p[7]);
            unsigned pc01 = cvtpk(p[8],  p[9]),  pc23 = cvtpk(p[10], p[11]);
            unsigned pd01 = cvtpk(p[12], p[13]), pd23 = cvtpk(p[14], p[15]);
            uint2v r0 = __builtin_amdgcn_permlane32_swap(pa01, pb01, false, false);
            uint2v r1 = __builtin_amdgcn_permlane32_swap(pa23, pb23, false, false);
            uint2v r2 = __builtin_amdgcn_permlane32_swap(pc01, pd01, false, false);
            uint2v r3 = __builtin_amdgcn_permlane32_swap(pc23, pd23, false, false);

            union { unsigned uu[4]; bf16x8 v; } pf0, pf1;
            pf0.uu[0] = r0[0];
            pf0.uu[1] = r1[0];
            pf0.uu[2] = r0[1];
            pf0.uu[3] = r1[1];
            pf1.uu[0] = r2[0];
            pf1.uu[1] = r3[0];
            pf1.uu[2] = r2[1];
            pf1.uu[3] = r3[1];

            #pragma unroll
            for (int d0 = 0; d0 < 4; ++d0) {
                const int row = d0 * 32 + lq;
                const int sw  = (lq >> 1) & 3;
                bf16x8 vf0 = *(const bf16x8*)(sVb + row * 64 + ((hi ^ sw) << 4));
                bf16x8 vf1 = *(const bf16x8*)(sVb + row * 64 + (((2 + hi) ^ sw) << 4));
                __builtin_amdgcn_s_setprio(1);
                o[d0] = __builtin_amdgcn_mfma_f32_32x32x16_bf16(vf0, pf0.v, o[d0], 0, 0, 0);
                o[d0] = __builtin_amdgcn_mfma_f32_32x32x16_bf16(vf1, pf1.v, o[d0], 0, 0, 0);
                __builtin_amdgcn_s_setprio(0);
            }
        }
    }

    if (w == 7) return;

    const float rl = 1.0f / l;
    unsigned short* orow = attnb + (long)(q0 + lq) * QD + (kh * NG + w) * DH;
    #pragma unroll
    for (int d0 = 0; d0 < 4; ++d0) {
        #pragma unroll
        for (int g = 0; g < 4; ++g) {
            ushort4 s4;
            s4.x = f2bf(o[d0][4 * g + 0] * rl);
            s4.y = f2bf(o[d0][4 * g + 1] * rl);
            s4.z = f2bf(o[d0][4 * g + 2] * rl);
            s4.w = f2bf(o[d0][4 * g + 3] * rl);
            *(ushort4*)(orow + d0 * 32 + 8 * g + hi4) = s4;
        }
    }
}

// ---------------- launch ----------------
extern "C" void kernel_launch(void* const* d_in, const int* in_sizes, int n_in,
                              void* d_out, int out_size, void* d_ws, size_t ws_size,
                              hipStream_t stream) {
    const int*   positions = (const int*)d_in[0];
    const float* hidden    = (const float*)d_in[1];
    const float* qkv_w     = (const float*)d_in[2];
    const float* qkv_b     = (const float*)d_in[3];
    const float* qnw       = (const float*)d_in[4];
    const float* knw       = (const float*)d_in[5];
    const float* o_w       = (const float*)d_in[6];
    float* out = (float*)d_out;

    unsigned char* ws = (unsigned char*)d_ws;
    unsigned short* hb    = (unsigned short*)(ws);               // 14,680,064 B
    unsigned short* w1    = (unsigned short*)(ws + 14680064);    // 33,030,144 B
    unsigned short* qkvb  = (unsigned short*)(ws + 47710208);    // 18,874,368 B (bf16 qkv)
    unsigned short* qbuf  = (unsigned short*)(ws + 85458944);    // 14,680,064 B
    unsigned short* kbuf  = (unsigned short*)(ws + 100139008);   //  2,097,152 B
    unsigned short* vtb   = (unsigned short*)(ws + 102236160);   //  2,097,152 B
    unsigned short* attnb = (unsigned short*)(ws);               // reuse hb (dead after GEMM1)
    unsigned short* w2    = (unsigned short*)(ws + 14680064);    // reuse w1 (dead after GEMM1)

    const int na4 = S_LEN * HIDDEN / 4;
    const int nb4 = NQKV * HIDDEN / 4;
    cvt2_f32_bf16<<<(na4 + nb4 + 255) / 256, 256, 0, stream>>>(hidden, hb, na4, qkv_w, w1, nb4);
    gemm_deep<192, true><<<dim3(NQKV / 192, S_LEN / 256), 512, 0, stream>>>(
        hb, w1, qkvb, qkv_b, S_LEN, NQKV, HIDDEN);
    qkv_post<<<S_LEN, 256, 0, stream>>>(qkvb, positions, qnw, knw, qbuf, kbuf, vtb);
    attn_fwd<<<dim3(64 + 16, NKH), 512, 0, stream>>>(qbuf, kbuf, vtb, attnb, o_w, w2);
    gemm_deep<128, false><<<dim3(HIDDEN / 128, S_LEN / 256), 512, 0, stream>>>(
        attnb, w2, out, nullptr, S_LEN, HIDDEN, QD);
}